// Round 1
// baseline (160.614 us; speedup 1.0000x reference)
//
#include <hip/hip_runtime.h>

namespace {

constexpr int BATCH = 8192;
constexpr int EMB   = 128;
constexpr int HID   = 512;
constexpr int ODIM  = 64;
constexpr float WBLEND = 1.0f / (7.0f * 0.5f);  // 2/7

// ---------------- kernel 1: transpose W_mods -> WT[m][i][o] ----------------
__global__ __launch_bounds__(256) void k_transpose(const float* __restrict__ W,
                                                   float* __restrict__ WT) {
  __shared__ float tile[128 * 129];
  const float* src = W + (size_t)blockIdx.x * 16384;
  float* dst = WT + (size_t)blockIdx.x * 16384;
  // read W[o][i] coalesced (i contiguous)
  for (int e = threadIdx.x; e < 16384; e += 256) {
    const int o = e >> 7, i = e & 127;
    tile[o * 129 + i] = src[e];
  }
  __syncthreads();
  // write WT[i][o] coalesced (o contiguous)
  for (int e = threadIdx.x; e < 16384; e += 256) {
    const int i = e >> 7, o = e & 127;
    dst[e] = tile[o * 129 + i];
  }
}

// ---------------- kernels 2-4: hop h (wave-per-element matvec) -------------
// x_next = relu(W_mods[mid[b,h]] @ x + E[eid[b,h+1]]); hop 2 fuses the blend.
template <int HOP>
__global__ __launch_bounds__(256) void k_hop(const float* __restrict__ E,
                                             const float* __restrict__ WT,
                                             const float* __restrict__ Xprev,
                                             const int* __restrict__ eids,
                                             const int* __restrict__ mids,
                                             float* __restrict__ Xnext) {
  __shared__ float xs[4][128];
  const int wv = threadIdx.x >> 6;
  const int l  = threadIdx.x & 63;
  const int b  = (blockIdx.x << 2) + wv;

  const int mid = mids[b * 3 + HOP];
  const float2* wt = (const float2*)(WT + (size_t)mid * 16384);

  const float* xsrc = (HOP == 0) ? (E + (size_t)eids[b * 4] * EMB)
                                 : (Xprev + (size_t)b * EMB);
  const float2 xv = ((const float2*)xsrc)[l];
  xs[wv][2 * l]     = xv.x;
  xs[wv][2 * l + 1] = xv.y;

  const float* bp = E + (size_t)eids[b * 4 + HOP + 1] * EMB;
  const float2 bias = ((const float2*)bp)[l];
  __syncthreads();

  float ax = 0.f, ay = 0.f;
#pragma unroll 8
  for (int i = 0; i < 128; ++i) {
    const float xi = xs[wv][i];              // LDS broadcast
    const float2 w2 = wt[i * 64 + l];        // coalesced 512B/wave
    ax = fmaf(w2.x, xi, ax);
    ay = fmaf(w2.y, xi, ay);
  }
  const float rx = fmaxf(ax + bias.x, 0.f);
  const float ry = fmaxf(ay + bias.y, 0.f);
  float2 o;
  if (HOP == 2) {
    o.x = (1.f - WBLEND) * bias.x + WBLEND * rx;
    o.y = (1.f - WBLEND) * bias.y + WBLEND * ry;
  } else {
    o.x = rx;
    o.y = ry;
  }
  ((float2*)(Xnext + (size_t)b * EMB))[l] = o;
}

// ---------------- kernel 5: H = relu(X @ W1^T + b1) ------------------------
// M=8192, N=512, K=128. 64x64 tile, full K staged, 4x4 register tiles.
constexpr int S1 = 129;  // padded LDS stride
__global__ __launch_bounds__(256) void k_mlp1(const float* __restrict__ X,
                                              const float* __restrict__ W1,
                                              const float* __restrict__ b1,
                                              float* __restrict__ H) {
  __shared__ float xs[64 * S1];
  __shared__ float ws[64 * S1];
  const int bm = blockIdx.x & 127;
  const int bn = blockIdx.x >> 7;
  const int row0 = bm * 64, col0 = bn * 64;

  for (int e = threadIdx.x; e < 2048; e += 256) {
    const int r = e >> 5, kq = e & 31;
    const float4 v = ((const float4*)(X + (size_t)(row0 + r) * EMB))[kq];
    float* d = &xs[r * S1 + kq * 4];
    d[0] = v.x; d[1] = v.y; d[2] = v.z; d[3] = v.w;
    const float4 u = ((const float4*)(W1 + (size_t)(col0 + r) * EMB))[kq];
    float* dw = &ws[r * S1 + kq * 4];
    dw[0] = u.x; dw[1] = u.y; dw[2] = u.z; dw[3] = u.w;
  }
  __syncthreads();

  const int tc = threadIdx.x & 15, tr = threadIdx.x >> 4;
  float acc[4][4] = {};
#pragma unroll 4
  for (int k = 0; k < 128; ++k) {
    float a[4], bb[4];
#pragma unroll
    for (int j = 0; j < 4; ++j) a[j] = xs[(tr * 4 + j) * S1 + k];
#pragma unroll
    for (int j = 0; j < 4; ++j) bb[j] = ws[(tc * 4 + j) * S1 + k];
#pragma unroll
    for (int p = 0; p < 4; ++p)
#pragma unroll
      for (int q = 0; q < 4; ++q) acc[p][q] = fmaf(a[p], bb[q], acc[p][q]);
  }

#pragma unroll
  for (int p = 0; p < 4; ++p) {
    const int row = row0 + tr * 4 + p;
    const int col = col0 + tc * 4;
    float4 o;
    o.x = fmaxf(acc[p][0] + b1[col + 0], 0.f);
    o.y = fmaxf(acc[p][1] + b1[col + 1], 0.f);
    o.z = fmaxf(acc[p][2] + b1[col + 2], 0.f);
    o.w = fmaxf(acc[p][3] + b1[col + 3], 0.f);
    *((float4*)(H + (size_t)row * HID + col)) = o;
  }
}

// ---------------- kernel 6: logits = H @ W2^T + b2 -------------------------
// M=8192, N=64 (full), K=512 in 4 chunks. 32x64 tile, 2x4 register tiles.
__global__ __launch_bounds__(256) void k_mlp2(const float* __restrict__ H,
                                              const float* __restrict__ W2,
                                              const float* __restrict__ b2,
                                              float* __restrict__ Out) {
  __shared__ float hs[32 * S1];
  __shared__ float ws[64 * S1];
  const int row0 = blockIdx.x * 32;
  const int tc = threadIdx.x & 15, tr = threadIdx.x >> 4;
  float acc[2][4] = {};

  for (int kt = 0; kt < 4; ++kt) {
    __syncthreads();
    for (int e = threadIdx.x; e < 1024; e += 256) {
      const int r = e >> 5, kq = e & 31;
      const float4 v =
          ((const float4*)(H + (size_t)(row0 + r) * HID + kt * 128))[kq];
      float* d = &hs[r * S1 + kq * 4];
      d[0] = v.x; d[1] = v.y; d[2] = v.z; d[3] = v.w;
    }
    for (int e = threadIdx.x; e < 2048; e += 256) {
      const int r = e >> 5, kq = e & 31;
      const float4 u =
          ((const float4*)(W2 + (size_t)r * HID + kt * 128))[kq];
      float* dw = &ws[r * S1 + kq * 4];
      dw[0] = u.x; dw[1] = u.y; dw[2] = u.z; dw[3] = u.w;
    }
    __syncthreads();
#pragma unroll 4
    for (int k = 0; k < 128; ++k) {
      float a[2], bb[4];
      a[0] = hs[(tr * 2 + 0) * S1 + k];
      a[1] = hs[(tr * 2 + 1) * S1 + k];
#pragma unroll
      for (int j = 0; j < 4; ++j) bb[j] = ws[(tc * 4 + j) * S1 + k];
#pragma unroll
      for (int p = 0; p < 2; ++p)
#pragma unroll
        for (int q = 0; q < 4; ++q) acc[p][q] = fmaf(a[p], bb[q], acc[p][q]);
    }
  }

#pragma unroll
  for (int p = 0; p < 2; ++p) {
    const int row = row0 + tr * 2 + p;
    const int col = tc * 4;
    float4 o;
    o.x = acc[p][0] + b2[col + 0];
    o.y = acc[p][1] + b2[col + 1];
    o.z = acc[p][2] + b2[col + 2];
    o.w = acc[p][3] + b2[col + 3];
    *((float4*)(Out + (size_t)row * ODIM + col)) = o;
  }
}

}  // namespace

extern "C" void kernel_launch(void* const* d_in, const int* in_sizes, int n_in,
                              void* d_out, int out_size, void* d_ws,
                              size_t ws_size, hipStream_t stream) {
  const float* E   = (const float*)d_in[0];
  const float* Wm  = (const float*)d_in[1];
  const float* W1  = (const float*)d_in[2];
  const float* b1  = (const float*)d_in[3];
  const float* W2  = (const float*)d_in[4];
  const float* b2  = (const float*)d_in[5];
  const int* eids  = (const int*)d_in[6];
  const int* mids  = (const int*)d_in[7];
  float* out = (float*)d_out;

  float* wsf = (float*)d_ws;
  float* WT = wsf;                    // 64*128*128   = 1,048,576 f32 (4 MB)
  float* X0 = wsf + 1048576;          // 8192*128     = 1,048,576 f32 (4 MB)
  float* X1 = wsf + 2 * 1048576;      // 8192*128     = 1,048,576 f32 (4 MB)
  float* Hb = wsf + 3 * 1048576;      // 8192*512     = 4,194,304 f32 (16 MB)

  k_transpose<<<dim3(64), dim3(256), 0, stream>>>(Wm, WT);
  k_hop<0><<<dim3(2048), dim3(256), 0, stream>>>(E, WT, nullptr, eids, mids, X0);
  k_hop<1><<<dim3(2048), dim3(256), 0, stream>>>(E, WT, X0, eids, mids, X1);
  k_hop<2><<<dim3(2048), dim3(256), 0, stream>>>(E, WT, X1, eids, mids, X0);
  k_mlp1<<<dim3(1024), dim3(256), 0, stream>>>(X0, W1, b1, Hb);
  k_mlp2<<<dim3(256), dim3(256), 0, stream>>>(Hb, W2, b2, out);
}

// Round 2
// 135.687 us; speedup vs baseline: 1.1837x; 1.1837x over previous
//
#include <hip/hip_runtime.h>

namespace {

constexpr int BATCH = 8192;
constexpr int EMB   = 128;
constexpr int HID   = 512;
constexpr int ODIM  = 64;
constexpr int NMOD  = 64;
constexpr int CAP   = 256;   // bucket capacity; Bin(8192,1/64) max ~170 << 256
constexpr float WB  = 1.0f / (7.0f * 0.5f);  // 2/7

// ws layout (float offsets)
constexpr size_t OFF_WT  = 0;                  // 64*128*128      (4 MB)  [i][o] k-major
constexpr size_t OFF_X0  = 1048576;            // 8192*128        (4 MB)
constexpr size_t OFF_X1  = 2 * 1048576;        // 8192*128        (4 MB)
constexpr size_t OFF_H   = 3 * 1048576;        // 8192*512        (16 MB)
constexpr size_t OFF_W1T = 7 * 1048576;        // 128*512         (256 KB) [k][col]
constexpr size_t OFF_W2T = OFF_W1T + 65536;    // 512*64          (128 KB) [k][col]
constexpr size_t OFF_CNT = OFF_W2T + 32768;    // 3*64 ints
constexpr size_t OFF_BKT = OFF_CNT + 256;      // 3*64*CAP ints   (192 KB)
// total ~28.6 MB

// ---------------- prep: transpose weights k-major + zero counters ----------
__global__ __launch_bounds__(256) void k_prep(const float* __restrict__ W,
                                              const float* __restrict__ W1,
                                              const float* __restrict__ W2,
                                              float* __restrict__ ws) {
  const int bx = blockIdx.x;
  if (bx < 64) {                       // W_mods[m] 128x128 -> WT[m] [i][o]
    __shared__ float t[128 * 129];
    const float* src = W + (size_t)bx * 16384;
    float* dst = ws + OFF_WT + (size_t)bx * 16384;
    for (int e = threadIdx.x; e < 16384; e += 256) {
      const int o = e >> 7, i = e & 127;
      t[o * 129 + i] = src[e];
    }
    __syncthreads();
    for (int e = threadIdx.x; e < 16384; e += 256) {
      const int i = e >> 7, o = e & 127;
      dst[e] = t[o * 129 + i];
    }
  } else if (bx < 72) {                // W1 [512][128] -> W1T [128][512]
    const int j = bx - 64;             // src rows [j*64, j*64+64)
    __shared__ float t[64 * 129];
    for (int e = threadIdx.x; e < 64 * 128; e += 256) {
      const int r = e >> 7, i = e & 127;
      t[r * 129 + i] = W1[(size_t)(j * 64 + r) * 128 + i];
    }
    __syncthreads();
    float* W1T = ws + OFF_W1T;
    for (int e = threadIdx.x; e < 128 * 16; e += 256) {
      const int i = e >> 4, r4 = e & 15;
      float4 v;
      v.x = t[(4 * r4 + 0) * 129 + i];
      v.y = t[(4 * r4 + 1) * 129 + i];
      v.z = t[(4 * r4 + 2) * 129 + i];
      v.w = t[(4 * r4 + 3) * 129 + i];
      *(float4*)&W1T[(size_t)i * 512 + j * 64 + 4 * r4] = v;
    }
  } else if (bx < 80) {                // W2 [64][512] -> W2T [512][64]
    const int j = bx - 72;             // k range [j*64, j*64+64)
    __shared__ float t[64 * 65];
    for (int e = threadIdx.x; e < 64 * 64; e += 256) {
      const int o = e >> 6, k = e & 63;
      t[o * 65 + k] = W2[(size_t)o * 512 + j * 64 + k];
    }
    __syncthreads();
    float* W2T = ws + OFF_W2T;
    for (int e = threadIdx.x; e < 64 * 16; e += 256) {
      const int k = e >> 4, o4 = e & 15;
      float4 v;
      v.x = t[(4 * o4 + 0) * 65 + k];
      v.y = t[(4 * o4 + 1) * 65 + k];
      v.z = t[(4 * o4 + 2) * 65 + k];
      v.w = t[(4 * o4 + 3) * 65 + k];
      *(float4*)&W2T[(size_t)(j * 64 + k) * 64 + 4 * o4] = v;
    }
  } else {                             // zero bucket counters
    int* cnt = (int*)(ws + OFF_CNT);
    if (threadIdx.x < 3 * NMOD) cnt[threadIdx.x] = 0;
  }
}

// ---------------- bucket: scatter batch ids by (hop, module) ---------------
__global__ __launch_bounds__(256) void k_bucket(const int* __restrict__ mids,
                                                float* __restrict__ ws) {
  int* cnt = (int*)(ws + OFF_CNT);
  int* bkt = (int*)(ws + OFF_BKT);
  const int idx = blockIdx.x * 256 + threadIdx.x;  // enumerates (b,h)
  if (idx >= BATCH * 3) return;
  const int b = idx / 3, h = idx - b * 3;
  const int m = mids[idx];
  const int pos = atomicAdd(&cnt[h * NMOD + m], 1);
  bkt[(h * NMOD + m) * CAP + pos] = b;
}

// ---------------- hop GEMM: per-module, 64 rows x 64 cols ------------------
// x_next = relu(W[m] @ x + E[eid[b,h+1]]); hop 2 fuses the blend.
template <int HOP>
__global__ __launch_bounds__(256) void k_hopg(const float* __restrict__ E,
                                              const int* __restrict__ eids,
                                              float* __restrict__ ws) {
  const int bx = blockIdx.x;
  const int m = bx >> 3, s = (bx >> 1) & 3, ch = bx & 1;
  const int* cnt = (const int*)(ws + OFF_CNT);
  const int cn = cnt[HOP * NMOD + m];
  if (s * 64 >= cn) return;

  const float* WT = ws + OFF_WT;
  const int* bkt = (const int*)(ws + OFF_BKT);
  const float* Xprev = ws + (HOP == 1 ? OFF_X0 : OFF_X1);  // hop0: unused
  float* Xnext = ws + (HOP == 1 ? OFF_X1 : OFF_X0);
  const int c0 = ch * 64;

  __shared__ float wsm[128 * 64];   // [k][64 cols of o] 32 KB
  __shared__ float xs[64 * 129];    // [row][k] padded   33 KB
  __shared__ int rows[64];

  for (int e = threadIdx.x; e < 128 * 16; e += 256) {
    const int k = e >> 4, c4 = e & 15;
    const float4 v =
        *(const float4*)&WT[(size_t)m * 16384 + k * 128 + c0 + 4 * c4];
    *(float4*)&wsm[k * 64 + 4 * c4] = v;
  }

  const int tr = threadIdx.x >> 4, tc = threadIdx.x & 15;

  for (int r0 = s * 64; r0 < cn; r0 += 256) {
    const int nr = min(64, cn - r0);
    __syncthreads();  // prev iter done with rows/xs (and wsm staged, iter 0)
    if (threadIdx.x < nr)
      rows[threadIdx.x] = bkt[(HOP * NMOD + m) * CAP + r0 + threadIdx.x];
    __syncthreads();
    for (int e = threadIdx.x; e < 64 * 32; e += 256) {
      const int row = e >> 5, i4 = e & 31;
      if (row < nr) {
        const int b = rows[row];
        const float* src = (HOP == 0) ? (E + (size_t)eids[b * 4] * EMB)
                                      : (Xprev + (size_t)b * EMB);
        const float4 v = *(const float4*)&src[4 * i4];
        float* d = &xs[row * 129 + 4 * i4];
        d[0] = v.x; d[1] = v.y; d[2] = v.z; d[3] = v.w;
      }
    }
    __syncthreads();

    float acc[4][4] = {};
#pragma unroll 4
    for (int k = 0; k < 128; ++k) {
      const float4 bv = *(const float4*)&wsm[k * 64 + tc * 4];
      const float a0 = xs[(tr * 4 + 0) * 129 + k];
      const float a1 = xs[(tr * 4 + 1) * 129 + k];
      const float a2 = xs[(tr * 4 + 2) * 129 + k];
      const float a3 = xs[(tr * 4 + 3) * 129 + k];
      acc[0][0] = fmaf(a0, bv.x, acc[0][0]);
      acc[0][1] = fmaf(a0, bv.y, acc[0][1]);
      acc[0][2] = fmaf(a0, bv.z, acc[0][2]);
      acc[0][3] = fmaf(a0, bv.w, acc[0][3]);
      acc[1][0] = fmaf(a1, bv.x, acc[1][0]);
      acc[1][1] = fmaf(a1, bv.y, acc[1][1]);
      acc[1][2] = fmaf(a1, bv.z, acc[1][2]);
      acc[1][3] = fmaf(a1, bv.w, acc[1][3]);
      acc[2][0] = fmaf(a2, bv.x, acc[2][0]);
      acc[2][1] = fmaf(a2, bv.y, acc[2][1]);
      acc[2][2] = fmaf(a2, bv.z, acc[2][2]);
      acc[2][3] = fmaf(a2, bv.w, acc[2][3]);
      acc[3][0] = fmaf(a3, bv.x, acc[3][0]);
      acc[3][1] = fmaf(a3, bv.y, acc[3][1]);
      acc[3][2] = fmaf(a3, bv.z, acc[3][2]);
      acc[3][3] = fmaf(a3, bv.w, acc[3][3]);
    }

#pragma unroll
    for (int p = 0; p < 4; ++p) {
      const int row = tr * 4 + p;
      if (row < nr) {
        const int b = rows[row];
        const float4 bias =
            *(const float4*)&E[(size_t)eids[b * 4 + HOP + 1] * EMB + c0 + tc * 4];
        float4 o;
        o.x = fmaxf(acc[p][0] + bias.x, 0.f);
        o.y = fmaxf(acc[p][1] + bias.y, 0.f);
        o.z = fmaxf(acc[p][2] + bias.z, 0.f);
        o.w = fmaxf(acc[p][3] + bias.w, 0.f);
        if (HOP == 2) {
          o.x = (1.f - WB) * bias.x + WB * o.x;
          o.y = (1.f - WB) * bias.y + WB * o.y;
          o.z = (1.f - WB) * bias.z + WB * o.z;
          o.w = (1.f - WB) * bias.w + WB * o.w;
        }
        *(float4*)&Xnext[(size_t)b * EMB + c0 + tc * 4] = o;
      }
    }
  }
}

// ---------------- mlp1: H = relu(X @ W1T + b1), 64x64 tiles ----------------
__global__ __launch_bounds__(256) void k_mlp1(const float* __restrict__ b1,
                                              float* __restrict__ ws) {
  const int rt = blockIdx.x >> 3, ct = blockIdx.x & 7;
  const float* X = ws + OFF_X0;
  const float* W1T = ws + OFF_W1T;
  float* H = ws + OFF_H;

  __shared__ float wsm[128 * 64];
  __shared__ float xs[64 * 129];

  for (int e = threadIdx.x; e < 128 * 16; e += 256) {
    const int k = e >> 4, c4 = e & 15;
    const float4 v = *(const float4*)&W1T[(size_t)k * 512 + ct * 64 + 4 * c4];
    *(float4*)&wsm[k * 64 + 4 * c4] = v;
  }
  for (int e = threadIdx.x; e < 64 * 32; e += 256) {
    const int row = e >> 5, i4 = e & 31;
    const float4 v = *(const float4*)&X[(size_t)(rt * 64 + row) * EMB + 4 * i4];
    float* d = &xs[row * 129 + 4 * i4];
    d[0] = v.x; d[1] = v.y; d[2] = v.z; d[3] = v.w;
  }
  __syncthreads();

  const int tr = threadIdx.x >> 4, tc = threadIdx.x & 15;
  float acc[4][4] = {};
#pragma unroll 4
  for (int k = 0; k < 128; ++k) {
    const float4 bv = *(const float4*)&wsm[k * 64 + tc * 4];
    const float a0 = xs[(tr * 4 + 0) * 129 + k];
    const float a1 = xs[(tr * 4 + 1) * 129 + k];
    const float a2 = xs[(tr * 4 + 2) * 129 + k];
    const float a3 = xs[(tr * 4 + 3) * 129 + k];
    acc[0][0] = fmaf(a0, bv.x, acc[0][0]);
    acc[0][1] = fmaf(a0, bv.y, acc[0][1]);
    acc[0][2] = fmaf(a0, bv.z, acc[0][2]);
    acc[0][3] = fmaf(a0, bv.w, acc[0][3]);
    acc[1][0] = fmaf(a1, bv.x, acc[1][0]);
    acc[1][1] = fmaf(a1, bv.y, acc[1][1]);
    acc[1][2] = fmaf(a1, bv.z, acc[1][2]);
    acc[1][3] = fmaf(a1, bv.w, acc[1][3]);
    acc[2][0] = fmaf(a2, bv.x, acc[2][0]);
    acc[2][1] = fmaf(a2, bv.y, acc[2][1]);
    acc[2][2] = fmaf(a2, bv.z, acc[2][2]);
    acc[2][3] = fmaf(a2, bv.w, acc[2][3]);
    acc[3][0] = fmaf(a3, bv.x, acc[3][0]);
    acc[3][1] = fmaf(a3, bv.y, acc[3][1]);
    acc[3][2] = fmaf(a3, bv.z, acc[3][2]);
    acc[3][3] = fmaf(a3, bv.w, acc[3][3]);
  }

  const float4 bb = *(const float4*)&b1[ct * 64 + tc * 4];
#pragma unroll
  for (int p = 0; p < 4; ++p) {
    float4 o;
    o.x = fmaxf(acc[p][0] + bb.x, 0.f);
    o.y = fmaxf(acc[p][1] + bb.y, 0.f);
    o.z = fmaxf(acc[p][2] + bb.z, 0.f);
    o.w = fmaxf(acc[p][3] + bb.w, 0.f);
    *(float4*)&H[(size_t)(rt * 64 + tr * 4 + p) * HID + ct * 64 + tc * 4] = o;
  }
}

// ---------------- mlp2: out = H @ W2T + b2, K=512 in 4 chunks --------------
__global__ __launch_bounds__(256) void k_mlp2(const float* __restrict__ b2,
                                              float* __restrict__ ws,
                                              float* __restrict__ Out) {
  const int rt = blockIdx.x;
  const float* H = ws + OFF_H;
  const float* W2T = ws + OFF_W2T;

  __shared__ float wsm[128 * 64];
  __shared__ float xs[64 * 129];

  const int tr = threadIdx.x >> 4, tc = threadIdx.x & 15;
  float acc[4][4] = {};

  for (int kc = 0; kc < 4; ++kc) {
    __syncthreads();
    for (int e = threadIdx.x; e < 128 * 16; e += 256) {
      const int k = e >> 4, c4 = e & 15;
      const float4 v =
          *(const float4*)&W2T[(size_t)(kc * 128 + k) * 64 + 4 * c4];
      *(float4*)&wsm[k * 64 + 4 * c4] = v;
    }
    for (int e = threadIdx.x; e < 64 * 32; e += 256) {
      const int row = e >> 5, i4 = e & 31;
      const float4 v =
          *(const float4*)&H[(size_t)(rt * 64 + row) * HID + kc * 128 + 4 * i4];
      float* d = &xs[row * 129 + 4 * i4];
      d[0] = v.x; d[1] = v.y; d[2] = v.z; d[3] = v.w;
    }
    __syncthreads();

#pragma unroll 4
    for (int k = 0; k < 128; ++k) {
      const float4 bv = *(const float4*)&wsm[k * 64 + tc * 4];
      const float a0 = xs[(tr * 4 + 0) * 129 + k];
      const float a1 = xs[(tr * 4 + 1) * 129 + k];
      const float a2 = xs[(tr * 4 + 2) * 129 + k];
      const float a3 = xs[(tr * 4 + 3) * 129 + k];
      acc[0][0] = fmaf(a0, bv.x, acc[0][0]);
      acc[0][1] = fmaf(a0, bv.y, acc[0][1]);
      acc[0][2] = fmaf(a0, bv.z, acc[0][2]);
      acc[0][3] = fmaf(a0, bv.w, acc[0][3]);
      acc[1][0] = fmaf(a1, bv.x, acc[1][0]);
      acc[1][1] = fmaf(a1, bv.y, acc[1][1]);
      acc[1][2] = fmaf(a1, bv.z, acc[1][2]);
      acc[1][3] = fmaf(a1, bv.w, acc[1][3]);
      acc[2][0] = fmaf(a2, bv.x, acc[2][0]);
      acc[2][1] = fmaf(a2, bv.y, acc[2][1]);
      acc[2][2] = fmaf(a2, bv.z, acc[2][2]);
      acc[2][3] = fmaf(a2, bv.w, acc[2][3]);
      acc[3][0] = fmaf(a3, bv.x, acc[3][0]);
      acc[3][1] = fmaf(a3, bv.y, acc[3][1]);
      acc[3][2] = fmaf(a3, bv.z, acc[3][2]);
      acc[3][3] = fmaf(a3, bv.w, acc[3][3]);
    }
  }

  const float4 bb = *(const float4*)&b2[tc * 4];
#pragma unroll
  for (int p = 0; p < 4; ++p) {
    float4 o;
    o.x = acc[p][0] + bb.x;
    o.y = acc[p][1] + bb.y;
    o.z = acc[p][2] + bb.z;
    o.w = acc[p][3] + bb.w;
    *(float4*)&Out[(size_t)(rt * 64 + tr * 4 + p) * ODIM + tc * 4] = o;
  }
}

}  // namespace

extern "C" void kernel_launch(void* const* d_in, const int* in_sizes, int n_in,
                              void* d_out, int out_size, void* d_ws,
                              size_t ws_size, hipStream_t stream) {
  const float* E  = (const float*)d_in[0];
  const float* Wm = (const float*)d_in[1];
  const float* W1 = (const float*)d_in[2];
  const float* b1 = (const float*)d_in[3];
  const float* W2 = (const float*)d_in[4];
  const float* b2 = (const float*)d_in[5];
  const int* eids = (const int*)d_in[6];
  const int* mids = (const int*)d_in[7];
  float* out = (float*)d_out;
  float* ws = (float*)d_ws;

  k_prep<<<dim3(81), dim3(256), 0, stream>>>(Wm, W1, W2, ws);
  k_bucket<<<dim3(96), dim3(256), 0, stream>>>(mids, ws);
  k_hopg<0><<<dim3(512), dim3(256), 0, stream>>>(E, eids, ws);
  k_hopg<1><<<dim3(512), dim3(256), 0, stream>>>(E, eids, ws);
  k_hopg<2><<<dim3(512), dim3(256), 0, stream>>>(E, eids, ws);
  k_mlp1<<<dim3(1024), dim3(256), 0, stream>>>(b1, ws);
  k_mlp2<<<dim3(128), dim3(256), 0, stream>>>(b2, ws, out);
}